// Round 4
// baseline (156.992 us; speedup 1.0000x reference)
//
#include <hip/hip_runtime.h>
#include <math.h>

#define FFT_N   4096
#define THREADS 256

// XOR swizzle: bijective within each 32-float row, <=2-way banks on all
// access patterns used below (2-way is free on CDNA4). No padding -> LDS
// is exactly 2*16KB = 32768 B -> 5 blocks/CU.
__device__ __forceinline__ int swz(int i) { return i ^ ((i >> 5) & 31); }

// Gperm[p] = ((W[k] + W[(N-k)%N])/2 + 1) / N  at  k = base16_digit_reverse(p)
__global__ void setup_g_kernel(const float* __restrict__ fw, float* __restrict__ gperm) {
    int p = blockIdx.x * blockDim.x + threadIdx.x;
    if (p >= FFT_N) return;
    unsigned k = ((p & 15u) << 8) | (p & 0xF0u) | ((unsigned)p >> 8);  // 3-digit base-16 reversal
    float wk  = fw[k];
    float wnk = fw[(FFT_N - k) & (FFT_N - 1)];
    gperm[p] = (0.5f * (wk + wnk) + 1.0f) * (1.0f / (float)FFT_N);
}

// in-register 16-point DFT, natural-order in/out.
// DIR=+1: W=e^{-2pi i/16} (forward). DIR=-1: unnormalized inverse.
template<int DIR>
__device__ __forceinline__ void dft16(float xr[16], float xi[16]) {
    const float C1 = 0.9238795325112867f;   // cos(pi/8)
    const float S1 = 0.3826834323650898f;   // sin(pi/8)
    const float H  = 0.7071067811865476f;
    const float TCt[10] = {1.f, C1, H, S1, 0.f, -S1, -H, -C1, -1.f, -C1};
    const float TSt[10] = {0.f, S1, H, C1, 1.f,  C1, H,  S1,  0.f, -S1};
    float tr[16], ti[16];
    #pragma unroll
    for (int m0 = 0; m0 < 4; ++m0) {
        float ar = xr[m0+ 0], ai = xi[m0+ 0];
        float br = xr[m0+ 4], bi = xi[m0+ 4];
        float cr = xr[m0+ 8], ci = xi[m0+ 8];
        float dr = xr[m0+12], di = xi[m0+12];
        float t0r = ar+cr, t0i = ai+ci;
        float t1r = ar-cr, t1i = ai-ci;
        float t2r = br+dr, t2i = bi+di;
        float t3r = br-dr, t3i = bi-di;
        float A0r = t0r+t2r, A0i = t0i+t2i;
        float A2r = t0r-t2r, A2i = t0i-t2i;
        float A1r, A1i, A3r, A3i;
        if (DIR > 0) { A1r = t1r + t3i; A1i = t1i - t3r; A3r = t1r - t3i; A3i = t1i + t3r; }
        else         { A1r = t1r - t3i; A1i = t1i + t3r; A3r = t1r + t3i; A3i = t1i - t3r; }
        tr[0*4+m0] = A0r; ti[0*4+m0] = A0i;
        {
            float c = TCt[m0], s = (DIR > 0) ? -TSt[m0] : TSt[m0];
            tr[1*4+m0] = A1r*c - A1i*s; ti[1*4+m0] = A1r*s + A1i*c;
        }
        {
            float c = TCt[2*m0], s = (DIR > 0) ? -TSt[2*m0] : TSt[2*m0];
            tr[2*4+m0] = A2r*c - A2i*s; ti[2*4+m0] = A2r*s + A2i*c;
        }
        {
            float c = TCt[3*m0], s = (DIR > 0) ? -TSt[3*m0] : TSt[3*m0];
            tr[3*4+m0] = A3r*c - A3i*s; ti[3*4+m0] = A3r*s + A3i*c;
        }
    }
    #pragma unroll
    for (int k0 = 0; k0 < 4; ++k0) {
        float ar = tr[k0*4+0], ai = ti[k0*4+0];
        float br = tr[k0*4+1], bi = ti[k0*4+1];
        float cr = tr[k0*4+2], ci = ti[k0*4+2];
        float dr = tr[k0*4+3], di = ti[k0*4+3];
        float t0r = ar+cr, t0i = ai+ci;
        float t1r = ar-cr, t1i = ai-ci;
        float t2r = br+dr, t2i = bi+di;
        float t3r = br-dr, t3i = bi-di;
        xr[k0+ 0] = t0r+t2r; xi[k0+ 0] = t0i+t2i;
        xr[k0+ 8] = t0r-t2r; xi[k0+ 8] = t0i-t2i;
        if (DIR > 0) {
            xr[k0+ 4] = t1r + t3i; xi[k0+ 4] = t1i - t3r;
            xr[k0+12] = t1r - t3i; xi[k0+12] = t1i + t3r;
        } else {
            xr[k0+ 4] = t1r - t3i; xi[k0+ 4] = t1i + t3r;
            xr[k0+12] = t1r + t3i; xi[k0+12] = t1i - t3r;
        }
    }
}

// multiply xr[k]+i*xi[k] by w^k, w = (cos ang, sin ang).
// Binary-power form: dependency depth ~5 instead of 15, same multiply count.
__device__ __forceinline__ void twiddle_apply(float xr[16], float xi[16], float ang) {
    float s1, c1;
    __sincosf(ang, &s1, &c1);
    float c2 = c1*c1 - s1*s1, s2 = 2.f*c1*s1;        // w^2
    float c3 = c2*c1 - s2*s1, s3 = c2*s1 + s2*c1;    // w^3
    float c4 = c2*c2 - s2*s2, s4 = 2.f*c2*s2;        // w^4
    { float tv = xr[1]; xr[1] = tv*c1 - xi[1]*s1; xi[1] = tv*s1 + xi[1]*c1; }
    { float tv = xr[2]; xr[2] = tv*c2 - xi[2]*s2; xi[2] = tv*s2 + xi[2]*c2; }
    { float tv = xr[3]; xr[3] = tv*c3 - xi[3]*s3; xi[3] = tv*s3 + xi[3]*c3; }
    float bc = c4, bs = s4;                           // base = w^(4q)
    #pragma unroll
    for (int q = 1; q < 4; ++q) {
        { float tv = xr[4*q]; xr[4*q] = tv*bc - xi[4*q]*bs; xi[4*q] = tv*bs + xi[4*q]*bc; }
        {
            float ec = bc*c1 - bs*s1, es = bc*s1 + bs*c1;
            float tv = xr[4*q+1]; xr[4*q+1] = tv*ec - xi[4*q+1]*es; xi[4*q+1] = tv*es + xi[4*q+1]*ec;
        }
        {
            float ec = bc*c2 - bs*s2, es = bc*s2 + bs*c2;
            float tv = xr[4*q+2]; xr[4*q+2] = tv*ec - xi[4*q+2]*es; xi[4*q+2] = tv*es + xi[4*q+2]*ec;
        }
        {
            float ec = bc*c3 - bs*s3, es = bc*s3 + bs*c3;
            float tv = xr[4*q+3]; xr[4*q+3] = tv*ec - xi[4*q+3]*es; xi[4*q+3] = tv*es + xi[4*q+3]*ec;
        }
        if (q < 3) { float nb = bc*c4 - bs*s4; bs = bc*s4 + bs*c4; bc = nb; }
    }
}

__global__ __launch_bounds__(THREADS, 5) void fourier_fft_kernel(
    const float* __restrict__ in, const float* __restrict__ gperm,
    const float* __restrict__ lw, float* __restrict__ out)
{
    __shared__ float re[FFT_N];
    __shared__ float im[FFT_N];
    const int t = threadIdx.x;
    const long long pair = blockIdx.x;
    const float* r0 = in + pair * (2LL * FFT_N);
    const float* r1 = r0 + FFT_N;

    const float CFA = -6.28318530717958647692f / 4096.0f;
    const float CFB = -6.28318530717958647692f / 256.0f;

    float xr[16], xi[16];

    // load: thread t owns x[t + 256k] — coalesced dword streams
    #pragma unroll
    for (int k = 0; k < 16; ++k) {
        xr[k] = r0[t + 256*k];
        xi[k] = r1[t + 256*k];
    }

    // ---- forward stage A (L=4096, j=t)
    dft16<1>(xr, xi);
    twiddle_apply(xr, xi, CFA * (float)t);
    #pragma unroll
    for (int k = 0; k < 16; ++k) { int s = swz(t + 256*k); re[s] = xr[k]; im[s] = xi[k]; }
    __syncthreads();

    // ---- forward stage B (L=256, j=t&15)
    const int jb = t & 15;
    const int baseB = (t >> 4)*256 + jb;
    #pragma unroll
    for (int k = 0; k < 16; ++k) { int s = swz(baseB + 16*k); xr[k] = re[s]; xi[k] = im[s]; }
    dft16<1>(xr, xi);
    twiddle_apply(xr, xi, CFB * (float)jb);
    #pragma unroll
    for (int k = 0; k < 16; ++k) { int s = swz(baseB + 16*k); re[s] = xr[k]; im[s] = xi[k]; }
    __syncthreads();

    // ---- forward stage C (L=16, unit twiddles) + pointwise G + inverse stage C'
    #pragma unroll
    for (int k = 0; k < 16; ++k) { int s = swz(16*t + k); xr[k] = re[s]; xi[k] = im[s]; }
    dft16<1>(xr, xi);
    {
        const float4* gp = (const float4*)(gperm + 16*t);
        #pragma unroll
        for (int q = 0; q < 4; ++q) {
            float4 g = gp[q];
            xr[4*q+0] *= g.x; xi[4*q+0] *= g.x;
            xr[4*q+1] *= g.y; xi[4*q+1] *= g.y;
            xr[4*q+2] *= g.z; xi[4*q+2] *= g.z;
            xr[4*q+3] *= g.w; xi[4*q+3] *= g.w;
        }
    }
    dft16<-1>(xr, xi);
    #pragma unroll
    for (int k = 0; k < 16; ++k) { int s = swz(16*t + k); re[s] = xr[k]; im[s] = xi[k]; }
    __syncthreads();

    // ---- inverse stage B' (L=256): conj twiddle on inputs, then IDFT16
    #pragma unroll
    for (int k = 0; k < 16; ++k) { int s = swz(baseB + 16*k); xr[k] = re[s]; xi[k] = im[s]; }
    twiddle_apply(xr, xi, -CFB * (float)jb);
    dft16<-1>(xr, xi);
    #pragma unroll
    for (int k = 0; k < 16; ++k) { int s = swz(baseB + 16*k); re[s] = xr[k]; im[s] = xi[k]; }
    __syncthreads();

    // ---- inverse stage A' (L=4096) + epilogue, straight from registers
    #pragma unroll
    for (int k = 0; k < 16; ++k) { int s = swz(t + 256*k); xr[k] = re[s]; xi[k] = im[s]; }
    twiddle_apply(xr, xi, -CFA * (float)t);
    dft16<-1>(xr, xi);

    float* o0 = out + pair * (2LL * FFT_N);
    #pragma unroll
    for (int k = 0; k < 16; ++k) {
        int i = t + 256*k;
        float l = lw[i];
        o0[i]         = fmaxf(xr[k]*l, 0.0f);
        o0[FFT_N + i] = fmaxf(xi[k]*l, 0.0f);
    }
}

extern "C" void kernel_launch(void* const* d_in, const int* in_sizes, int n_in,
                              void* d_out, int out_size, void* d_ws, size_t ws_size,
                              hipStream_t stream) {
    const float* inputs = (const float*)d_in[0];
    const float* fw     = (const float*)d_in[1];
    const float* lw     = (const float*)d_in[2];
    float* out   = (float*)d_out;
    float* gperm = (float*)d_ws;   // 4096 floats = 16 KB scratch

    hipLaunchKernelGGL(setup_g_kernel, dim3(FFT_N / THREADS), dim3(THREADS), 0, stream,
                       fw, gperm);

    const int pairs = in_sizes[0] / (2 * FFT_N);   // 16384 rows -> 8192 pairs
    hipLaunchKernelGGL(fourier_fft_kernel, dim3(pairs), dim3(THREADS), 0, stream,
                       inputs, gperm, lw, out);
}

// Round 5
// 124.513 us; speedup vs baseline: 1.2609x; 1.2609x over previous
//
#include <hip/hip_runtime.h>
#include <math.h>

#define FFT_N   4096
#define THREADS 512

// Two-term XOR swizzle: bijective (only bits 0-4 change, driven by higher
// bits), <=2-way banks on ALL four stage patterns (A/B/C/D) -> conflict-free
// in practice (2-way is free on CDNA4). No padding -> LDS = 32768 B exactly.
__device__ __forceinline__ int swz(int i) {
    return i ^ ((i >> 5) & 31) ^ (((i >> 6) & 7) << 2);
}

// Gperm[p] = ((W[k] + W[(N-k)%N])/2 + 1) / N  at  k = base8_digit_reverse(p)
__global__ void setup_g_kernel(const float* __restrict__ fw, float* __restrict__ gperm) {
    int p = blockIdx.x * blockDim.x + threadIdx.x;
    if (p >= FFT_N) return;
    unsigned k = ((p & 7u) << 9) | (((p >> 3) & 7u) << 6) | (((p >> 6) & 7u) << 3) | ((p >> 9) & 7u);
    float wk  = fw[k];
    float wnk = fw[(FFT_N - k) & (FFT_N - 1)];
    gperm[p] = (0.5f * (wk + wnk) + 1.0f) * (1.0f / (float)FFT_N);
}

// 8-point DFT, natural order in/out. DIR=+1: W=e^{-2pi i/8}; DIR=-1: unnormalized inverse.
template<int DIR>
__device__ __forceinline__ void dft8(float xr[8], float xi[8]) {
    const float H = 0.7071067811865476f;
    float u0r = xr[0]+xr[4], u0i = xi[0]+xi[4];
    float u1r = xr[1]+xr[5], u1i = xi[1]+xi[5];
    float u2r = xr[2]+xr[6], u2i = xi[2]+xi[6];
    float u3r = xr[3]+xr[7], u3i = xi[3]+xi[7];
    float v0r = xr[0]-xr[4], v0i = xi[0]-xi[4];
    float v1r = xr[1]-xr[5], v1i = xi[1]-xi[5];
    float v2r = xr[2]-xr[6], v2i = xi[2]-xi[6];
    float v3r = xr[3]-xr[7], v3i = xi[3]-xi[7];
    // v1 *= W8^DIR ; v2 *= W8^{2 DIR} (= -+i) ; v3 *= W8^{3 DIR}
    {
        float r = v1r, m = v1i;
        if (DIR > 0) { v1r = H*(r + m); v1i = H*(m - r); }
        else         { v1r = H*(r - m); v1i = H*(m + r); }
    }
    {
        float r = v2r, m = v2i;
        if (DIR > 0) { v2r = m;  v2i = -r; }
        else         { v2r = -m; v2i = r;  }
    }
    {
        float r = v3r, m = v3i;
        if (DIR > 0) { v3r = H*(m - r);  v3i = -H*(m + r); }
        else         { v3r = -H*(m + r); v3i = H*(r - m);  }
    }
    // dft4 natural on u -> X[0,2,4,6]
    {
        float t0r=u0r+u2r, t0i=u0i+u2i, t1r=u0r-u2r, t1i=u0i-u2i;
        float t2r=u1r+u3r, t2i=u1i+u3i, t3r=u1r-u3r, t3i=u1i-u3i;
        xr[0]=t0r+t2r; xi[0]=t0i+t2i;
        xr[4]=t0r-t2r; xi[4]=t0i-t2i;
        if (DIR>0) { xr[2]=t1r+t3i; xi[2]=t1i-t3r; xr[6]=t1r-t3i; xi[6]=t1i+t3r; }
        else       { xr[2]=t1r-t3i; xi[2]=t1i+t3r; xr[6]=t1r+t3i; xi[6]=t1i-t3r; }
    }
    // dft4 natural on v -> X[1,3,5,7]
    {
        float t0r=v0r+v2r, t0i=v0i+v2i, t1r=v0r-v2r, t1i=v0i-v2i;
        float t2r=v1r+v3r, t2i=v1i+v3i, t3r=v1r-v3r, t3i=v1i-v3i;
        xr[1]=t0r+t2r; xi[1]=t0i+t2i;
        xr[5]=t0r-t2r; xi[5]=t0i-t2i;
        if (DIR>0) { xr[3]=t1r+t3i; xi[3]=t1i-t3r; xr[7]=t1r-t3i; xi[7]=t1i+t3r; }
        else       { xr[3]=t1r-t3i; xi[3]=t1i+t3r; xr[7]=t1r+t3i; xi[7]=t1i-t3r; }
    }
}

// multiply slot k by w^k, w = (cos ang, sin ang); serial chain, 4 regs.
__device__ __forceinline__ void twiddle8(float xr[8], float xi[8], float ang) {
    float s1, c1; __sincosf(ang, &s1, &c1);
    float wc = c1, ws = s1;
    #pragma unroll
    for (int k = 1; k < 8; ++k) {
        float tv = xr[k];
        xr[k] = tv*wc - xi[k]*ws;
        xi[k] = tv*ws + xi[k]*wc;
        if (k < 7) { float nc = wc*c1 - ws*s1; ws = wc*s1 + ws*c1; wc = nc; }
    }
}

__global__ __launch_bounds__(THREADS, 6) void fourier_fft_kernel(
    const float* __restrict__ in, const float* __restrict__ gperm,
    const float* __restrict__ lw, float* __restrict__ out)
{
    __shared__ float re[FFT_N];
    __shared__ float im[FFT_N];
    const int t = threadIdx.x;
    const long long pair = blockIdx.x;
    const float* r0 = in + pair * (2LL * FFT_N);
    const float* r1 = r0 + FFT_N;

    const float CFA = -6.28318530717958647692f / 4096.0f;
    const float CFB = -6.28318530717958647692f / 512.0f;
    const float CFC = -6.28318530717958647692f / 64.0f;

    float xr[8], xi[8];

    // load: thread t owns x[t + 512k] — coalesced
    #pragma unroll
    for (int k = 0; k < 8; ++k) {
        xr[k] = r0[t + 512*k];
        xi[k] = r1[t + 512*k];
    }

    // ---- forward stage A (L=4096, M=512, j=t)
    dft8<1>(xr, xi);
    twiddle8(xr, xi, CFA * (float)t);
    #pragma unroll
    for (int k = 0; k < 8; ++k) { int s = swz(t + 512*k); re[s] = xr[k]; im[s] = xi[k]; }
    __syncthreads();

    // ---- forward stage B (L=512, M=64, g=t>>6, j=t&63)
    const int baseB = ((t >> 6) << 9) + (t & 63);
    #pragma unroll
    for (int k = 0; k < 8; ++k) { int s = swz(baseB + 64*k); xr[k] = re[s]; xi[k] = im[s]; }
    dft8<1>(xr, xi);
    twiddle8(xr, xi, CFB * (float)(t & 63));
    #pragma unroll
    for (int k = 0; k < 8; ++k) { int s = swz(baseB + 64*k); re[s] = xr[k]; im[s] = xi[k]; }
    __syncthreads();

    // ---- forward stage C (L=64, M=8, g=t>>3, j=t&7)
    const int baseC = ((t >> 3) << 6) + (t & 7);
    #pragma unroll
    for (int k = 0; k < 8; ++k) { int s = swz(baseC + 8*k); xr[k] = re[s]; xi[k] = im[s]; }
    dft8<1>(xr, xi);
    twiddle8(xr, xi, CFC * (float)(t & 7));
    #pragma unroll
    for (int k = 0; k < 8; ++k) { int s = swz(baseC + 8*k); re[s] = xr[k]; im[s] = xi[k]; }
    __syncthreads();

    // ---- forward stage D (L=8, unit twiddles) + pointwise G + inverse stage D'
    #pragma unroll
    for (int k = 0; k < 8; ++k) { int s = swz(8*t + k); xr[k] = re[s]; xi[k] = im[s]; }
    dft8<1>(xr, xi);
    {
        const float4* gp = (const float4*)(gperm + 8*t);
        float4 g0 = gp[0], g1 = gp[1];
        xr[0] *= g0.x; xi[0] *= g0.x;  xr[1] *= g0.y; xi[1] *= g0.y;
        xr[2] *= g0.z; xi[2] *= g0.z;  xr[3] *= g0.w; xi[3] *= g0.w;
        xr[4] *= g1.x; xi[4] *= g1.x;  xr[5] *= g1.y; xi[5] *= g1.y;
        xr[6] *= g1.z; xi[6] *= g1.z;  xr[7] *= g1.w; xi[7] *= g1.w;
    }
    dft8<-1>(xr, xi);
    #pragma unroll
    for (int k = 0; k < 8; ++k) { int s = swz(8*t + k); re[s] = xr[k]; im[s] = xi[k]; }
    __syncthreads();

    // ---- inverse stage C' (conj twiddle on inputs, then idft8)
    #pragma unroll
    for (int k = 0; k < 8; ++k) { int s = swz(baseC + 8*k); xr[k] = re[s]; xi[k] = im[s]; }
    twiddle8(xr, xi, -CFC * (float)(t & 7));
    dft8<-1>(xr, xi);
    #pragma unroll
    for (int k = 0; k < 8; ++k) { int s = swz(baseC + 8*k); re[s] = xr[k]; im[s] = xi[k]; }
    __syncthreads();

    // ---- inverse stage B'
    #pragma unroll
    for (int k = 0; k < 8; ++k) { int s = swz(baseB + 64*k); xr[k] = re[s]; xi[k] = im[s]; }
    twiddle8(xr, xi, -CFB * (float)(t & 63));
    dft8<-1>(xr, xi);
    #pragma unroll
    for (int k = 0; k < 8; ++k) { int s = swz(baseB + 64*k); re[s] = xr[k]; im[s] = xi[k]; }
    __syncthreads();

    // ---- inverse stage A' + epilogue straight from registers
    #pragma unroll
    for (int k = 0; k < 8; ++k) { int s = swz(t + 512*k); xr[k] = re[s]; xi[k] = im[s]; }
    twiddle8(xr, xi, -CFA * (float)t);
    dft8<-1>(xr, xi);

    float* o0 = out + pair * (2LL * FFT_N);
    #pragma unroll
    for (int k = 0; k < 8; ++k) {
        int i = t + 512*k;
        float l = lw[i];
        o0[i]         = fmaxf(xr[k]*l, 0.0f);
        o0[FFT_N + i] = fmaxf(xi[k]*l, 0.0f);
    }
}

extern "C" void kernel_launch(void* const* d_in, const int* in_sizes, int n_in,
                              void* d_out, int out_size, void* d_ws, size_t ws_size,
                              hipStream_t stream) {
    const float* inputs = (const float*)d_in[0];
    const float* fw     = (const float*)d_in[1];
    const float* lw     = (const float*)d_in[2];
    float* out   = (float*)d_out;
    float* gperm = (float*)d_ws;   // 4096 floats = 16 KB scratch

    hipLaunchKernelGGL(setup_g_kernel, dim3(FFT_N / 256), dim3(256), 0, stream,
                       fw, gperm);

    const int pairs = in_sizes[0] / (2 * FFT_N);   // 16384 rows -> 8192 pairs
    hipLaunchKernelGGL(fourier_fft_kernel, dim3(pairs), dim3(THREADS), 0, stream,
                       inputs, gperm, lw, out);
}